// Round 12
// baseline (178.562 us; speedup 1.0000x reference)
//
#include <hip/hip_runtime.h>

#define BB 8
#define FF 64
#define NN 2048
#define EPS 1e-7f
#define PTCH 4
#define BT 128                      // output tile edge
#define NT (NN / BT)                // 16 tile-cols

typedef float f32x4 __attribute__((ext_vector_type(4)));  // native clang vec

// ---------------------------------------------------------------------------
// DIAGNOSTIC ROUND: full 2048-block grid, normal (coalesced) stores only —
// no triangular decode, no mirror-store transpose. Purpose: wij has been
// invisible in top-5 (75 us < 84-86 us poison fills) for 3 rounds while
// sitting 3.5x above the issue-rate model; at ~142 us this variant surfaces
// its PMC row (VALUBusy / FETCH / WRITE / conflicts / occupancy) and the
// per-block time vs r11 isolates the mirror-store cost. Inner loop, LDS
// layout, epilogue identical to r11.
// ---------------------------------------------------------------------------
__global__ __launch_bounds__(256, 2) void wij_kernel(
    const float* __restrict__ emb, float* __restrict__ out) {
  __shared__ float As[FF][BT];  // 32 KB
  __shared__ float Bs[FF][BT];  // 32 KB
  __shared__ float sm[4];

  const int it = blockIdx.x / NT;
  const int jt = blockIdx.x % NT;
  const int b = blockIdx.y;
  const int i0 = it * BT;
  const int j0 = jt * BT;
  const int tid = threadIdx.x;
  const int tx = tid & 15;   // col group
  const int ty = tid >> 4;   // row group

  const float* embB = emb + (size_t)b * FF * NN;

  // --- fused dmin, part 1: issue the 8 f=4-row loads first (coalesced) ---
  const float* row4 = embB + (size_t)PTCH * NN;
  float x0 = row4[tid], x1 = row4[tid + 256], x2 = row4[tid + 512],
        x3 = row4[tid + 768], x4 = row4[tid + 1024], x5 = row4[tid + 1280],
        x6 = row4[tid + 1536], x7 = row4[tid + 1792];

  // Stage both 64x128 tiles: 2 x 2048 f32x4, 8 each per thread, coalesced.
#pragma unroll
  for (int r = 0; r < 8; ++r) {
    const int idx = tid + 256 * r;      // f32x4 index, 0..2047
    const int f = idx >> 5;             // 32 f32x4 per row -> f 0..63
    const int col = (idx & 31) * 4;
    *(f32x4*)&As[f][col] = *(const f32x4*)&embB[(size_t)f * NN + i0 + col];
    *(f32x4*)&Bs[f][col] = *(const f32x4*)&embB[(size_t)f * NN + j0 + col];
  }

  // --- fused dmin, part 2: wave reduce + publish partials (pre-barrier) ---
  float pmin = fminf(fminf(fminf(x0 * x0, x1 * x1), fminf(x2 * x2, x3 * x3)),
                     fminf(fminf(x4 * x4, x5 * x5), fminf(x6 * x6, x7 * x7)));
#pragma unroll
  for (int off = 32; off > 0; off >>= 1)
    pmin = fminf(pmin, __shfl_down(pmin, off, 64));
  if ((tid & 63) == 0) sm[tid >> 6] = pmin;

  __syncthreads();  // covers staging and sm[]

  const float dm = fminf(fminf(sm[0], sm[1]), fminf(sm[2], sm[3])) + EPS;
  const float inv = 1.0f / dm;

  const f32x4 vzero = {0.f, 0.f, 0.f, 0.f};
  f32x4 acc[2][2][4];  // [ri][rj][m], vector lanes = n
#pragma unroll
  for (int ri = 0; ri < 2; ++ri)
#pragma unroll
    for (int rj = 0; rj < 2; ++rj)
#pragma unroll
      for (int m = 0; m < 4; ++m) acc[ri][rj][m] = vzero;
  f32x4 niv[2] = {vzero, vzero};  // lanes = m
  f32x4 njv[2] = {vzero, vzero};  // lanes = n

#pragma unroll 4
  for (int f = 0; f < FF; ++f) {
    const f32x4 a0 = *(const f32x4*)&As[f][ty * 4];
    const f32x4 a1 = *(const f32x4*)&As[f][64 + ty * 4];
    const f32x4 b0 = *(const f32x4*)&Bs[f][tx * 4];
    const f32x4 b1 = *(const f32x4*)&Bs[f][64 + tx * 4];
    niv[0] += a0 * a0;
    niv[1] += a1 * a1;
    njv[0] += b0 * b0;
    njv[1] += b1 * b1;
#pragma unroll
    for (int m = 0; m < 4; ++m) {
      acc[0][0][m] += a0[m] * b0;
      acc[0][1][m] += a0[m] * b1;
      acc[1][0][m] += a1[m] * b0;
      acc[1][1][m] += a1[m] * b1;
    }
  }

  // pm fragments: f=4 rows of the LDS tiles, squared.
  const f32x4 a40 = *(const f32x4*)&As[PTCH][ty * 4];
  const f32x4 a41 = *(const f32x4*)&As[PTCH][64 + ty * 4];
  const f32x4 b40 = *(const f32x4*)&Bs[PTCH][tx * 4];
  const f32x4 b41 = *(const f32x4*)&Bs[PTCH][64 + tx * 4];
  const f32x4 piv[2] = {a40 * a40, a41 * a41};  // lanes = m
  const f32x4 pjv[2] = {b40 * b40, b41 * b41};  // lanes = n

  // acc -> w in place:  w = exp(-((sq*mm - dm)/dm)) = exp(1 - sq*mm*inv)
#pragma unroll
  for (int ri = 0; ri < 2; ++ri)
#pragma unroll
    for (int rj = 0; rj < 2; ++rj)
#pragma unroll
      for (int m = 0; m < 4; ++m) {
        const f32x4 v = acc[ri][rj][m];
        f32x4 w;
#pragma unroll
        for (int n = 0; n < 4; ++n) {
          float sq = fmaf(-2.0f, v[n], niv[ri][m] + njv[rj][n]);
          float mm = fminf(piv[ri][m], pjv[rj][n]);
          w[n] = __expf(fmaf(sq * mm, -inv, 1.0f));
        }
        acc[ri][rj][m] = w;
      }

  float* outB = out + (size_t)b * NN * NN;

  // Coalesced store only (non-temporal).
#pragma unroll
  for (int ri = 0; ri < 2; ++ri)
#pragma unroll
    for (int m = 0; m < 4; ++m) {
      const size_t row = (size_t)(i0 + ri * 64 + ty * 4 + m) * NN;
#pragma unroll
      for (int rj = 0; rj < 2; ++rj)
        __builtin_nontemporal_store(acc[ri][rj][m],
                                    (f32x4*)&outB[row + j0 + rj * 64 + tx * 4]);
    }
}

// ---------------------------------------------------------------------------
extern "C" void kernel_launch(void* const* d_in, const int* in_sizes, int n_in,
                              void* d_out, int out_size, void* d_ws,
                              size_t ws_size, hipStream_t stream) {
  const float* emb = (const float*)d_in[0];
  float* out = (float*)d_out;
  (void)d_ws; (void)ws_size; (void)in_sizes; (void)n_in; (void)out_size;

  wij_kernel<<<dim3(NT * NT, BB), 256, 0, stream>>>(emb, out);
}

// Round 13
// 165.796 us; speedup vs baseline: 1.0770x; 1.0770x over previous
//
#include <hip/hip_runtime.h>

#define BB 8
#define FF 64
#define FH 32                       // K-split half depth
#define NN 2048
#define EPS 1e-7f
#define PTCH 4
#define BT 128                      // output tile edge
#define NT (NN / BT)                // 16 tile-cols
#define NTRI (NT * (NT + 1) / 2)    // 136 upper-tri tiles

typedef float f32x4 __attribute__((ext_vector_type(4)));  // native clang vec

// ---------------------------------------------------------------------------
// r13: K-SPLIT LDS staging -> 33 KB/block -> 4 blocks/CU (was 64 KB, 2).
// Hypothesis: at 2 waves/SIMD the loop is latency-bound (issue model 18 us,
// measured <=66; r9->r11 delta was a latency effect). 4 waves/SIMD doubles
// wave-level hiding. Staging runs in two phases (f 0..31, 32..63) with the
// pm row (f=4) parked in a 1 KB LDS buffer so its 16 values stay off the
// loop's register live-range (__launch_bounds__(256,4) caps VGPR at 128).
// Shape reverted to r11's triangular+mirror (r12 proved it -17 us vs full).
// Everything else unchanged: fused dmin, in-register norms, fused epilogue,
// non-temporal stores, register-transposed mirror.
// ---------------------------------------------------------------------------
__global__ __launch_bounds__(256, 4) void wij_kernel(
    const float* __restrict__ emb, float* __restrict__ out) {
  __shared__ float As[FH][BT];   // 16 KB
  __shared__ float Bs[FH][BT];   // 16 KB
  __shared__ float pmbuf[2 * BT];  // 1 KB: [0..127]=pm_i, [128..255]=pm_j
  __shared__ float sm[4];

  // decode upper-triangular tile index (block-uniform scalar loop)
  int t = blockIdx.x, it = 0;
  while (t >= NT - it) { t -= NT - it; ++it; }
  const int jt = it + t;
  const int b = blockIdx.y;
  const int i0 = it * BT;
  const int j0 = jt * BT;
  const int tid = threadIdx.x;
  const int tx = tid & 15;   // col group
  const int ty = tid >> 4;   // row group

  const float* embB = emb + (size_t)b * FF * NN;

  // --- fused dmin, part 1: issue the 8 f=4-row loads first (coalesced) ---
  const float* row4 = embB + (size_t)PTCH * NN;
  float x0 = row4[tid], x1 = row4[tid + 256], x2 = row4[tid + 512],
        x3 = row4[tid + 768], x4 = row4[tid + 1024], x5 = row4[tid + 1280],
        x6 = row4[tid + 1536], x7 = row4[tid + 1792];

  // Stage half 0 (f = 0..31): 2 x 1024 f32x4, 4 each per thread, coalesced.
#pragma unroll
  for (int r = 0; r < 4; ++r) {
    const int idx = tid + 256 * r;      // 0..1023
    const int fl = idx >> 5;            // 0..31
    const int col = (idx & 31) * 4;
    const size_t gofs = (size_t)fl * NN;
    *(f32x4*)&As[fl][col] = *(const f32x4*)&embB[gofs + i0 + col];
    *(f32x4*)&Bs[fl][col] = *(const f32x4*)&embB[gofs + j0 + col];
  }

  // --- fused dmin, part 2: wave reduce + publish partials (pre-barrier) ---
  float pmin = fminf(fminf(fminf(x0 * x0, x1 * x1), fminf(x2 * x2, x3 * x3)),
                     fminf(fminf(x4 * x4, x5 * x5), fminf(x6 * x6, x7 * x7)));
#pragma unroll
  for (int off = 32; off > 0; off >>= 1)
    pmin = fminf(pmin, __shfl_down(pmin, off, 64));
  if ((tid & 63) == 0) sm[tid >> 6] = pmin;

  __syncthreads();  // staging(half0) + sm[] complete

  const float dm = fminf(fminf(sm[0], sm[1]), fminf(sm[2], sm[3])) + EPS;
  const float inv = 1.0f / dm;

  // Park the pm row (f=4, lives in half 0) in LDS: 1 value per thread.
  pmbuf[tid] = (tid < BT) ? As[PTCH][tid] * As[PTCH][tid]
                          : Bs[PTCH][tid - BT] * Bs[PTCH][tid - BT];

  const f32x4 vzero = {0.f, 0.f, 0.f, 0.f};
  f32x4 acc[2][2][4];  // [ri][rj][m], vector lanes = n
#pragma unroll
  for (int ri = 0; ri < 2; ++ri)
#pragma unroll
    for (int rj = 0; rj < 2; ++rj)
#pragma unroll
      for (int m = 0; m < 4; ++m) acc[ri][rj][m] = vzero;
  f32x4 niv[2] = {vzero, vzero};  // lanes = m
  f32x4 njv[2] = {vzero, vzero};  // lanes = n

  // ---- compute half 0 ----
#pragma unroll 4
  for (int fl = 0; fl < FH; ++fl) {
    const f32x4 a0 = *(const f32x4*)&As[fl][ty * 4];
    const f32x4 a1 = *(const f32x4*)&As[fl][64 + ty * 4];
    const f32x4 b0 = *(const f32x4*)&Bs[fl][tx * 4];
    const f32x4 b1 = *(const f32x4*)&Bs[fl][64 + tx * 4];
    niv[0] += a0 * a0;
    niv[1] += a1 * a1;
    njv[0] += b0 * b0;
    njv[1] += b1 * b1;
#pragma unroll
    for (int m = 0; m < 4; ++m) {
      acc[0][0][m] += a0[m] * b0;
      acc[0][1][m] += a0[m] * b1;
      acc[1][0][m] += a1[m] * b0;
      acc[1][1][m] += a1[m] * b1;
    }
  }

  __syncthreads();  // all reads of half 0 done (pmbuf also globally visible)

  // Stage half 1 (f = 32..63).
#pragma unroll
  for (int r = 0; r < 4; ++r) {
    const int idx = tid + 256 * r;
    const int fl = idx >> 5;
    const int col = (idx & 31) * 4;
    const size_t gofs = (size_t)(FH + fl) * NN;
    *(f32x4*)&As[fl][col] = *(const f32x4*)&embB[gofs + i0 + col];
    *(f32x4*)&Bs[fl][col] = *(const f32x4*)&embB[gofs + j0 + col];
  }

  __syncthreads();  // staging(half1) complete

  // ---- compute half 1 ----
#pragma unroll 4
  for (int fl = 0; fl < FH; ++fl) {
    const f32x4 a0 = *(const f32x4*)&As[fl][ty * 4];
    const f32x4 a1 = *(const f32x4*)&As[fl][64 + ty * 4];
    const f32x4 b0 = *(const f32x4*)&Bs[fl][tx * 4];
    const f32x4 b1 = *(const f32x4*)&Bs[fl][64 + tx * 4];
    niv[0] += a0 * a0;
    niv[1] += a1 * a1;
    njv[0] += b0 * b0;
    njv[1] += b1 * b1;
#pragma unroll
    for (int m = 0; m < 4; ++m) {
      acc[0][0][m] += a0[m] * b0;
      acc[0][1][m] += a0[m] * b1;
      acc[1][0][m] += a1[m] * b0;
      acc[1][1][m] += a1[m] * b1;
    }
  }

  // pm fragments from the parked LDS buffer.
  const f32x4 piv[2] = {*(const f32x4*)&pmbuf[ty * 4],
                        *(const f32x4*)&pmbuf[64 + ty * 4]};        // lanes=m
  const f32x4 pjv[2] = {*(const f32x4*)&pmbuf[BT + tx * 4],
                        *(const f32x4*)&pmbuf[BT + 64 + tx * 4]};   // lanes=n

  // acc -> w in place:  w = exp(-((sq*mm - dm)/dm)) = exp(1 - sq*mm*inv)
#pragma unroll
  for (int ri = 0; ri < 2; ++ri)
#pragma unroll
    for (int rj = 0; rj < 2; ++rj)
#pragma unroll
      for (int m = 0; m < 4; ++m) {
        const f32x4 v = acc[ri][rj][m];
        f32x4 w;
#pragma unroll
        for (int n = 0; n < 4; ++n) {
          float sq = fmaf(-2.0f, v[n], niv[ri][m] + njv[rj][n]);
          float mm = fminf(piv[ri][m], pjv[rj][n]);
          w[n] = __expf(fmaf(sq * mm, -inv, 1.0f));
        }
        acc[ri][rj][m] = w;
      }

  float* outB = out + (size_t)b * NN * NN;

  // Normal store (non-temporal): rows i0+ri*64+ty*4+m, cols j0+rj*64+tx*4..
#pragma unroll
  for (int ri = 0; ri < 2; ++ri)
#pragma unroll
    for (int m = 0; m < 4; ++m) {
      const size_t row = (size_t)(i0 + ri * 64 + ty * 4 + m) * NN;
#pragma unroll
      for (int rj = 0; rj < 2; ++rj)
        __builtin_nontemporal_store(acc[ri][rj][m],
                                    (f32x4*)&outB[row + j0 + rj * 64 + tx * 4]);
    }

  // Mirror store (transpose, non-temporal), skipped on diagonal tiles.
  if (it != jt) {
#pragma unroll
    for (int rj = 0; rj < 2; ++rj)
#pragma unroll
      for (int n = 0; n < 4; ++n) {
        const size_t row = (size_t)(j0 + rj * 64 + tx * 4 + n) * NN;
#pragma unroll
        for (int ri = 0; ri < 2; ++ri) {
          f32x4 v = {acc[ri][rj][0][n], acc[ri][rj][1][n], acc[ri][rj][2][n],
                     acc[ri][rj][3][n]};
          __builtin_nontemporal_store(
              v, (f32x4*)&outB[row + i0 + ri * 64 + ty * 4]);
        }
      }
  }
}

// ---------------------------------------------------------------------------
extern "C" void kernel_launch(void* const* d_in, const int* in_sizes, int n_in,
                              void* d_out, int out_size, void* d_ws,
                              size_t ws_size, hipStream_t stream) {
  const float* emb = (const float*)d_in[0];
  float* out = (float*)d_out;
  (void)d_ws; (void)ws_size; (void)in_sizes; (void)n_in; (void)out_size;

  wij_kernel<<<dim3(NTRI, BB), 256, 0, stream>>>(emb, out);
}